// Round 7
// baseline (216.699 us; speedup 1.0000x reference)
//
#include <hip/hip_runtime.h>

// VersorRotorRNN: B=16, S=256, N=16, D=6, H=16, 32 blades (Cl(5,0)).
// Segmented parallel scan over S. normalize() is scale-invariant; GP is
// bilinear+associative -> defer normalization; scan the segment products.
//
// R2+R4 lesson: NEVER set min-waves>=2 (VGPR cap -> spill).
// R5 lesson: per-thread LDS weight reads saturate the CU LDS pipe.
// R6 lesson: wave-per-h (scalar weights, no LDS) works: VGPR 72, conflicts 0,
//   VALUBusy 60% — but grid supplies only 8 waves/CU (occ 15%).
// R7: SEGT 32->64 doubles waves (16/CU, ~50% occ), halves per-thread work.

#define EPS 1e-8f

struct SgnTab { float v[32][32]; };
constexpr SgnTab make_sgn() {
    SgnTab t{};
    for (int i = 0; i < 32; ++i)
        for (int j = 0; j < 32; ++j) {
            int a = i >> 1, s = 0;
            while (a) {
                int x = a & j;
                while (x) { s += x & 1; x >>= 1; }
                a >>= 1;
            }
            t.v[i][j] = (s & 1) ? -1.0f : 1.0f;
        }
    return t;
}
__device__ constexpr SgnTab SG = make_sgn();

__device__ __forceinline__ float inv_norm(const float* v) {
    float s0 = 0.f, s1 = 0.f, s2 = 0.f, s3 = 0.f;
#pragma unroll
    for (int k = 0; k < 32; k += 4) {
        s0 = fmaf(v[k],     v[k],     s0);
        s1 = fmaf(v[k + 1], v[k + 1], s1);
        s2 = fmaf(v[k + 2], v[k + 2], s2);
        s3 = fmaf(v[k + 3], v[k + 3], s3);
    }
    return rsqrtf((s0 + s1) + (s2 + s3) + EPS);
}

// np += (u8 chunk c8) (x) R : np[i^j] += sgn(i,j)*u8[l]*R[j], i=c8*8+l
__device__ __forceinline__ void gp_chunk(float* __restrict__ np,
                                         const float u8[8],
                                         const float* __restrict__ R, int c8) {
#pragma unroll
    for (int l = 0; l < 8; ++l) {
        const int i = c8 * 8 + l;
#pragma unroll
        for (int j = 0; j < 32; ++j)
            np[i ^ j] = fmaf(SG.v[i][j] * u8[l], R[j], np[i ^ j]);
    }
}

// Wave wid: h = wid&15, g = (wid>>4)&3, s = wid>>6 (0..SEGT-1).
// Lane = bn-chain within group g (bn = g*64+lane; bn = b*16+n).
// Weights indexed by h only -> wave-uniform -> scalar/K$ loads, no LDS.

// u8 = chunk c8 of  b_in[h] + x.W_in[:, h*32+..]  (+1 on blade 0)
__device__ __forceinline__ void build_u8_s(const float* __restrict__ Wh,
                                           const float* __restrict__ Bh,
                                           int c8, const float xv[6], float u8[8]) {
#pragma unroll
    for (int l = 0; l < 8; ++l) u8[l] = Bh[c8 * 8 + l];
#pragma unroll
    for (int d = 0; d < 6; ++d)
#pragma unroll
        for (int l = 0; l < 8; ++l)
            u8[l] = fmaf(xv[d], Wh[d * 512 + c8 * 8 + l], u8[l]);
    if (c8 == 0) u8[0] += 1.0f;
}

// Q layout: [s][h][bn][32]  (coalesced store/load)
template <int SEGT>
__global__ __launch_bounds__(256, 1) void k_seg2(
        const float* __restrict__ x, const float* __restrict__ W_in,
        const float* __restrict__ b_in, float* __restrict__ Q) {
    constexpr int L = 256 / SEGT;
    const int lane = threadIdx.x & 63;
    const int wid = __builtin_amdgcn_readfirstlane(
        (int)(blockIdx.x * 4 + (threadIdx.x >> 6)));
    const int h = wid & 15, g = (wid >> 4) & 3, s = wid >> 6;
    const int bn = g * 64 + lane, b = bn >> 4, n = bn & 15;
    const float* __restrict__ Wh = W_in + h * 32;  // [d*512 + c]
    const float* __restrict__ Bh = b_in + h * 32;

    float P[32];
    {   // step 0: P = u_0  (1 (x) u = u)
        const int t = s * L;
        const float2* xp = (const float2*)(x + ((b * 256 + t) * 16 + n) * 6);
        float2 x01 = xp[0], x23 = xp[1], x45 = xp[2];
        const float xv[6] = {x01.x, x01.y, x23.x, x23.y, x45.x, x45.y};
#pragma unroll
        for (int c8 = 0; c8 < 4; ++c8) build_u8_s(Wh, Bh, c8, xv, P + c8 * 8);
    }
#pragma unroll
    for (int i = 1; i < L; ++i) {
        const int t = s * L + i;
        const float2* xp = (const float2*)(x + ((b * 256 + t) * 16 + n) * 6);
        float2 x01 = xp[0], x23 = xp[1], x45 = xp[2];
        const float xv[6] = {x01.x, x01.y, x23.x, x23.y, x45.x, x45.y};
        float np[32];
#pragma unroll
        for (int k = 0; k < 32; ++k) np[k] = 0.0f;
#pragma unroll
        for (int c8 = 0; c8 < 4; ++c8) {
            float u8[8];
            build_u8_s(Wh, Bh, c8, xv, u8);
            gp_chunk(np, u8, P, c8);
        }
#pragma unroll
        for (int k = 0; k < 32; ++k) P[k] = np[k];  // raw; norm deferred
    }
    float rs = inv_norm(P);
    float4* qp = (float4*)(Q + (((s * 16 + h) * 256) + bn) * 32);
#pragma unroll
    for (int r = 0; r < 8; ++r)
        qp[r] = make_float4(P[4 * r] * rs, P[4 * r + 1] * rs,
                            P[4 * r + 2] * rs, P[4 * r + 3] * rs);
}

// Kogge-Stone exclusive scan over s (SEGT lanes per chain)
template <int SEGT>
__global__ __launch_bounds__(256, 1) void k_scan2(float* __restrict__ Q) {
    const unsigned u = blockIdx.x * 256 + threadIdx.x;
    const int s = u & (SEGT - 1);
    const unsigned chain = u / SEGT;        // bn*16 + h
    const int h = chain & 15, bn = chain >> 4;
    float* base = Q + (((s * 16 + h) * 256) + bn) * 32;

    float xr[32];
    {
        const float4* qp = (const float4*)base;
#pragma unroll
        for (int r = 0; r < 8; ++r) {
            float4 v = qp[r];
            xr[4 * r] = v.x; xr[4 * r + 1] = v.y;
            xr[4 * r + 2] = v.z; xr[4 * r + 3] = v.w;
        }
    }
#pragma unroll
    for (int k = 1; k < SEGT; k <<= 1) {
        float pr[32];
#pragma unroll
        for (int j = 0; j < 32; ++j) pr[j] = __shfl_up(xr[j], k, SEGT);
        if (s >= k) {
            float np[32];
#pragma unroll
            for (int m = 0; m < 32; ++m) np[m] = 0.0f;
#pragma unroll
            for (int i = 0; i < 32; ++i)
#pragma unroll
                for (int j = 0; j < 32; ++j)
                    np[i ^ j] = fmaf(SG.v[i][j] * xr[i], pr[j], np[i ^ j]);
#pragma unroll
            for (int m = 0; m < 32; ++m) xr[m] = np[m];
        }
    }
    {   // single normalization of the inclusive prefix
        float rs = inv_norm(xr);
#pragma unroll
        for (int j = 0; j < 32; ++j) xr[j] *= rs;
    }
    float er[32];
#pragma unroll
    for (int j = 0; j < 32; ++j) er[j] = __shfl_up(xr[j], 1, SEGT);
    if (s == 0) {
#pragma unroll
        for (int j = 0; j < 32; ++j) er[j] = 0.0f;
        er[0] = 1.0f;  // identity rotor
    }
    float4* qp = (float4*)base;
#pragma unroll
    for (int r = 0; r < 8; ++r)
        qp[r] = make_float4(er[4 * r], er[4 * r + 1],
                            er[4 * r + 2], er[4 * r + 3]);
}

// apply interior + project; write per-(t,h,bn) partials to WS2[t][h][bn][6]
template <int SEGT>
__global__ __launch_bounds__(256, 1) void k_apply2(
        const float* __restrict__ x, const float* __restrict__ W_in,
        const float* __restrict__ b_in, const float* __restrict__ W_out,
        const float* __restrict__ Pre, float* __restrict__ WS2) {
    constexpr int L = 256 / SEGT;
    const int lane = threadIdx.x & 63;
    const int wid = __builtin_amdgcn_readfirstlane(
        (int)(blockIdx.x * 4 + (threadIdx.x >> 6)));
    const int h = wid & 15, g = (wid >> 4) & 3, s = wid >> 6;
    const int bn = g * 64 + lane, b = bn >> 4, n = bn & 15;
    const float* __restrict__ Wh = W_in + h * 32;
    const float* __restrict__ Bh = b_in + h * 32;
    const float* __restrict__ Oh = W_out + h * 192;  // [k*6 + d]

    float R[32];
    {
        const float4* pp = (const float4*)(Pre + (((s * 16 + h) * 256) + bn) * 32);
#pragma unroll
        for (int r = 0; r < 8; ++r) {
            float4 v = pp[r];
            R[4 * r] = v.x; R[4 * r + 1] = v.y;
            R[4 * r + 2] = v.z; R[4 * r + 3] = v.w;
        }
    }
#pragma unroll
    for (int i = 0; i < L; ++i) {
        const int t = s * L + i;
        const float2* xp = (const float2*)(x + ((b * 256 + t) * 16 + n) * 6);
        float2 x01 = xp[0], x23 = xp[1], x45 = xp[2];
        const float xv[6] = {x01.x, x01.y, x23.x, x23.y, x45.x, x45.y};
        float np[32];
#pragma unroll
        for (int k = 0; k < 32; ++k) np[k] = 0.0f;
#pragma unroll
        for (int c8 = 0; c8 < 4; ++c8) {
            float u8[8];
            build_u8_s(Wh, Bh, c8, xv, u8);
            gp_chunk(np, u8, R, c8);
        }
        float rs = inv_norm(np);     // fold psi normalization into pd
        float pd[6] = {0.f, 0.f, 0.f, 0.f, 0.f, 0.f};
#pragma unroll
        for (int k = 0; k < 32; ++k)
#pragma unroll
            for (int d = 0; d < 6; ++d)
                pd[d] = fmaf(np[k], Oh[k * 6 + d], pd[d]);
#pragma unroll
        for (int k = 0; k < 32; ++k) R[k] = np[k];  // carry raw psi
        float2* wp = (float2*)(WS2 + (((t * 16 + h) * 256) + bn) * 6);
        wp[0] = make_float2(pd[0] * rs, pd[1] * rs);
        wp[1] = make_float2(pd[2] * rs, pd[3] * rs);
        wp[2] = make_float2(pd[4] * rs, pd[5] * rs);
    }
}

// out[o] = x[o] + b_out[d] + sum_h WS2[t][h][bn][d]   (o = ((b*256+t)*16+n)*6+d)
__global__ __launch_bounds__(256, 1) void k_reduce(
        const float* __restrict__ x, const float* __restrict__ b_out,
        const float* __restrict__ WS2, float* __restrict__ out) {
    const int o = blockIdx.x * 256 + threadIdx.x;  // 393216 total
    const int d = o % 6;
    const int r = o / 6;
    const int n = r & 15;
    const int r2 = r >> 4;
    const int t = r2 & 255;
    const int b = r2 >> 8;
    const int bn = b * 16 + n;
    float acc = x[o] + b_out[d];
#pragma unroll
    for (int h = 0; h < 16; ++h)
        acc += WS2[(((t * 16 + h) * 256) + bn) * 6 + d];
    out[o] = acc;
}

extern "C" void kernel_launch(void* const* d_in, const int* in_sizes, int n_in,
                              void* d_out, int out_size, void* d_ws, size_t ws_size,
                              hipStream_t stream) {
    (void)in_sizes; (void)n_in; (void)out_size;
    const float* x     = (const float*)d_in[0];  // [16,256,16,6]
    const float* W_in  = (const float*)d_in[1];  // [6,512]
    const float* b_in  = (const float*)d_in[2];  // [512]
    const float* W_out = (const float*)d_in[3];  // [512,6]
    const float* b_out = (const float*)d_in[4];  // [6]
    float* out = (float*)d_out;                  // [16,256,16,6]

    const size_t wsBytes = 256UL * 16 * 256 * 6 * sizeof(float);   // 24 MB
    const size_t q64 = 4096UL * 64 * 32 * sizeof(float);           // 32 MB
    const size_t q32 = 4096UL * 32 * 32 * sizeof(float);           // 16 MB

    if (ws_size >= q64 + wsBytes) {           // 56 MB: SEGT=64 path
        float* Q   = (float*)d_ws;
        float* WS2 = (float*)((char*)d_ws + q64);
        k_seg2<64>  <<<1024, 256, 0, stream>>>(x, W_in, b_in, Q);
        k_scan2<64> <<<1024, 256, 0, stream>>>(Q);
        k_apply2<64><<<1024, 256, 0, stream>>>(x, W_in, b_in, W_out, Q, WS2);
        k_reduce    <<<1536, 256, 0, stream>>>(x, b_out, WS2, out);
    } else {                                   // 40 MB: R6 (proven) path
        float* Q   = (float*)d_ws;
        float* WS2 = (float*)((char*)d_ws + q32);
        k_seg2<32>  <<<512,  256, 0, stream>>>(x, W_in, b_in, Q);
        k_scan2<32> <<<512,  256, 0, stream>>>(Q);
        k_apply2<32><<<512,  256, 0, stream>>>(x, W_in, b_in, W_out, Q, WS2);
        k_reduce    <<<1536, 256, 0, stream>>>(x, b_out, WS2, out);
    }
}

// Round 8
// 199.618 us; speedup vs baseline: 1.0856x; 1.0856x over previous
//
#include <hip/hip_runtime.h>

// VersorRotorRNN: B=16, S=256, N=16, D=6, H=16, 32 blades (Cl(5,0)).
// Segmented parallel scan over S (SEGT=32, L=8). normalize() is
// scale-invariant; GP bilinear+associative -> defer normalization.
//
// R2+R4: NEVER min-waves>=2 in __launch_bounds__ (VGPR cap -> spill).
// R5: per-thread LDS weight reads saturate the CU LDS pipe -> no LDS.
// R6: wave-per-h scalar-weight path works (VGPR 72, VALUBusy 60%).
// R7: SEGT=64 regressed: 16 distinct h/CU x 1.7 KB = 27 KB > 16 KB sK$
//     -> scalar-cache thrash, VALUBusy 47%. Keep SEGT=32.
// R8: h uniform PER BLOCK (2 h/CU = 3.4 KB, always K$-hit) + trims:
//     GP init-by-mul (sgn(0,j)=+1), ping-pong psi buffers, x prefetch.

#define EPS 1e-8f

struct SgnTab { float v[32][32]; };
constexpr SgnTab make_sgn() {
    SgnTab t{};
    for (int i = 0; i < 32; ++i)
        for (int j = 0; j < 32; ++j) {
            int a = i >> 1, s = 0;
            while (a) {
                int x = a & j;
                while (x) { s += x & 1; x >>= 1; }
                a >>= 1;
            }
            t.v[i][j] = (s & 1) ? -1.0f : 1.0f;
        }
    return t;
}
__device__ constexpr SgnTab SG = make_sgn();

__device__ __forceinline__ float inv_norm(const float* v) {
    float s0 = 0.f, s1 = 0.f, s2 = 0.f, s3 = 0.f;
#pragma unroll
    for (int k = 0; k < 32; k += 4) {
        s0 = fmaf(v[k],     v[k],     s0);
        s1 = fmaf(v[k + 1], v[k + 1], s1);
        s2 = fmaf(v[k + 2], v[k + 2], s2);
        s3 = fmaf(v[k + 3], v[k + 3], s3);
    }
    return rsqrtf((s0 + s1) + (s2 + s3) + EPS);
}

// u8 = chunk c8 of  b_in[h] + x.W_in[:, h*32+..]  (+1 on blade 0)
__device__ __forceinline__ void build_u8_s(const float* __restrict__ Wh,
                                           const float* __restrict__ Bh,
                                           int c8, const float xv[6], float u8[8]) {
#pragma unroll
    for (int l = 0; l < 8; ++l) u8[l] = Bh[c8 * 8 + l];
#pragma unroll
    for (int d = 0; d < 6; ++d)
#pragma unroll
        for (int l = 0; l < 8; ++l)
            u8[l] = fmaf(xv[d], Wh[d * 512 + c8 * 8 + l], u8[l]);
    if (c8 == 0) u8[0] += 1.0f;
}

// dst = u(x) (x) src  — full GP, dst INITIALIZED by the i=0 row
// (sgn(0,j)=+1 => dst[j] = u[0]*src[j]); src untouched, dst != src.
__device__ __forceinline__ void gp_step(const float* __restrict__ Wh,
                                        const float* __restrict__ Bh,
                                        const float xv[6],
                                        const float* __restrict__ src,
                                        float* __restrict__ dst) {
    {
        float u8[8];
        build_u8_s(Wh, Bh, 0, xv, u8);
#pragma unroll
        for (int j = 0; j < 32; ++j) dst[j] = u8[0] * src[j];
#pragma unroll
        for (int l = 1; l < 8; ++l) {
#pragma unroll
            for (int j = 0; j < 32; ++j)
                dst[l ^ j] = fmaf(SG.v[l][j] * u8[l], src[j], dst[l ^ j]);
        }
    }
#pragma unroll
    for (int c8 = 1; c8 < 4; ++c8) {
        float u8[8];
        build_u8_s(Wh, Bh, c8, xv, u8);
#pragma unroll
        for (int l = 0; l < 8; ++l) {
            const int i = c8 * 8 + l;
#pragma unroll
            for (int j = 0; j < 32; ++j)
                dst[i ^ j] = fmaf(SG.v[i][j] * u8[l], src[j], dst[i ^ j]);
        }
    }
}

// Block blk: h = blk&15 (uniform over block!), s = blk>>4, g = wave-in-block.
// Lane = bn-chain (bn = g*64+lane; b = bn>>4, n = bn&15).
// Q layout: [s][h][bn][32]  (coalesced store/load)

__global__ __launch_bounds__(256, 1) void k_seg2(
        const float* __restrict__ x, const float* __restrict__ W_in,
        const float* __restrict__ b_in, float* __restrict__ Q) {
    constexpr int L = 8;
    const int lane = threadIdx.x & 63;
    const int h = blockIdx.x & 15;               // block-uniform
    const int s = blockIdx.x >> 4;               // 0..31
    const int g = __builtin_amdgcn_readfirstlane((int)(threadIdx.x >> 6));
    const int bn = g * 64 + lane, b = bn >> 4, n = bn & 15;
    const float* __restrict__ Wh = W_in + h * 32;  // [d*512 + c]
    const float* __restrict__ Bh = b_in + h * 32;

    const float2* xp = (const float2*)(x + ((b * 256 + s * L) * 16 + n) * 6);
    float2 px0 = xp[0], px1 = xp[1], px2 = xp[2];   // prefetched step-0 x

    float A[32], Bf[32];
    {   // step 0: A = u_0  (1 (x) u = u)
        const float xv[6] = {px0.x, px0.y, px1.x, px1.y, px2.x, px2.y};
        xp += 48;  px0 = xp[0]; px1 = xp[1]; px2 = xp[2];  // prefetch step 1
#pragma unroll
        for (int c8 = 0; c8 < 4; ++c8) build_u8_s(Wh, Bh, c8, xv, A + c8 * 8);
    }
#pragma unroll
    for (int i = 1; i < L; ++i) {
        const float xv[6] = {px0.x, px0.y, px1.x, px1.y, px2.x, px2.y};
        if (i + 1 < L) { xp += 48; px0 = xp[0]; px1 = xp[1]; px2 = xp[2]; }
        const float* src = (i & 1) ? A : Bf;
        float*       dst = (i & 1) ? Bf : A;
        gp_step(Wh, Bh, xv, src, dst);
    }
    const float* P = ((L - 1) & 1) ? Bf : A;   // L=8 -> Bf
    float rs = inv_norm(P);
    float4* qp = (float4*)(Q + (((s * 16 + h) * 256) + bn) * 32);
#pragma unroll
    for (int r = 0; r < 8; ++r)
        qp[r] = make_float4(P[4 * r] * rs, P[4 * r + 1] * rs,
                            P[4 * r + 2] * rs, P[4 * r + 3] * rs);
}

// Kogge-Stone exclusive scan over s (32 lanes per chain, 2 chains/wave)
__global__ __launch_bounds__(256, 1) void k_scan2(float* __restrict__ Q) {
    const unsigned u = blockIdx.x * 256 + threadIdx.x;
    const int s = u & 31;
    const unsigned chain = u >> 5;          // bn*16 + h
    const int h = chain & 15, bn = chain >> 4;
    float* base = Q + (((s * 16 + h) * 256) + bn) * 32;

    float xr[32];
    {
        const float4* qp = (const float4*)base;
#pragma unroll
        for (int r = 0; r < 8; ++r) {
            float4 v = qp[r];
            xr[4 * r] = v.x; xr[4 * r + 1] = v.y;
            xr[4 * r + 2] = v.z; xr[4 * r + 3] = v.w;
        }
    }
#pragma unroll
    for (int k = 1; k < 32; k <<= 1) {
        float pr[32];
#pragma unroll
        for (int j = 0; j < 32; ++j) pr[j] = __shfl_up(xr[j], k, 32);
        if (s >= k) {
            float np[32];
#pragma unroll
            for (int j = 0; j < 32; ++j) np[j] = xr[0] * pr[j];  // i=0 row
#pragma unroll
            for (int i = 1; i < 32; ++i)
#pragma unroll
                for (int j = 0; j < 32; ++j)
                    np[i ^ j] = fmaf(SG.v[i][j] * xr[i], pr[j], np[i ^ j]);
#pragma unroll
            for (int m = 0; m < 32; ++m) xr[m] = np[m];
        }
    }
    {   // single normalization of the inclusive prefix
        float rs = inv_norm(xr);
#pragma unroll
        for (int j = 0; j < 32; ++j) xr[j] *= rs;
    }
    float er[32];
#pragma unroll
    for (int j = 0; j < 32; ++j) er[j] = __shfl_up(xr[j], 1, 32);
    if (s == 0) {
#pragma unroll
        for (int j = 0; j < 32; ++j) er[j] = 0.0f;
        er[0] = 1.0f;  // identity rotor
    }
    float4* qp = (float4*)base;
#pragma unroll
    for (int r = 0; r < 8; ++r)
        qp[r] = make_float4(er[4 * r], er[4 * r + 1],
                            er[4 * r + 2], er[4 * r + 3]);
}

// apply interior + project; write per-(t,h,bn) partials to WS2[t][h][bn][6]
__global__ __launch_bounds__(256, 1) void k_apply2(
        const float* __restrict__ x, const float* __restrict__ W_in,
        const float* __restrict__ b_in, const float* __restrict__ W_out,
        const float* __restrict__ Pre, float* __restrict__ WS2) {
    constexpr int L = 8;
    const int lane = threadIdx.x & 63;
    const int h = blockIdx.x & 15;               // block-uniform
    const int s = blockIdx.x >> 4;               // 0..31
    const int g = __builtin_amdgcn_readfirstlane((int)(threadIdx.x >> 6));
    const int bn = g * 64 + lane, b = bn >> 4, n = bn & 15;
    const float* __restrict__ Wh = W_in + h * 32;
    const float* __restrict__ Bh = b_in + h * 32;
    const float* __restrict__ Oh = W_out + h * 192;  // [k*6 + d]

    float A[32], Bf[32];
    {
        const float4* pp = (const float4*)(Pre + (((s * 16 + h) * 256) + bn) * 32);
#pragma unroll
        for (int r = 0; r < 8; ++r) {
            float4 v = pp[r];
            A[4 * r] = v.x; A[4 * r + 1] = v.y;
            A[4 * r + 2] = v.z; A[4 * r + 3] = v.w;
        }
    }
    const float2* xp = (const float2*)(x + ((b * 256 + s * L) * 16 + n) * 6);
    float2 px0 = xp[0], px1 = xp[1], px2 = xp[2];

#pragma unroll
    for (int i = 0; i < L; ++i) {
        const int t = s * L + i;
        const float xv[6] = {px0.x, px0.y, px1.x, px1.y, px2.x, px2.y};
        if (i + 1 < L) { xp += 48; px0 = xp[0]; px1 = xp[1]; px2 = xp[2]; }
        const float* src = (i & 1) ? Bf : A;
        float*       dst = (i & 1) ? A : Bf;
        gp_step(Wh, Bh, xv, src, dst);       // dst = raw psi_t
        float rs = inv_norm(dst);            // fold normalization into pd
        float pd[6] = {0.f, 0.f, 0.f, 0.f, 0.f, 0.f};
#pragma unroll
        for (int k = 0; k < 32; ++k)
#pragma unroll
            for (int d = 0; d < 6; ++d)
                pd[d] = fmaf(dst[k], Oh[k * 6 + d], pd[d]);
        float2* wp = (float2*)(WS2 + (((t * 16 + h) * 256) + bn) * 6);
        wp[0] = make_float2(pd[0] * rs, pd[1] * rs);
        wp[1] = make_float2(pd[2] * rs, pd[3] * rs);
        wp[2] = make_float2(pd[4] * rs, pd[5] * rs);
    }
}

// out[o] = x[o] + b_out[d] + sum_h WS2[t][h][bn][d]   (o = ((b*256+t)*16+n)*6+d)
__global__ __launch_bounds__(256, 1) void k_reduce(
        const float* __restrict__ x, const float* __restrict__ b_out,
        const float* __restrict__ WS2, float* __restrict__ out) {
    const int o = blockIdx.x * 256 + threadIdx.x;  // 393216 total
    const int d = o % 6;
    const int r = o / 6;
    const int n = r & 15;
    const int r2 = r >> 4;
    const int t = r2 & 255;
    const int b = r2 >> 8;
    const int bn = b * 16 + n;
    float acc = x[o] + b_out[d];
#pragma unroll
    for (int h = 0; h < 16; ++h)
        acc += WS2[(((t * 16 + h) * 256) + bn) * 6 + d];
    out[o] = acc;
}

extern "C" void kernel_launch(void* const* d_in, const int* in_sizes, int n_in,
                              void* d_out, int out_size, void* d_ws, size_t ws_size,
                              hipStream_t stream) {
    (void)in_sizes; (void)n_in; (void)out_size; (void)ws_size;
    const float* x     = (const float*)d_in[0];  // [16,256,16,6]
    const float* W_in  = (const float*)d_in[1];  // [6,512]
    const float* b_in  = (const float*)d_in[2];  // [512]
    const float* W_out = (const float*)d_in[3];  // [512,6]
    const float* b_out = (const float*)d_in[4];  // [6]
    float* out = (float*)d_out;                  // [16,256,16,6]

    const size_t q32 = 4096UL * 32 * 32 * sizeof(float);           // 16 MB
    float* Q   = (float*)d_ws;
    float* WS2 = (float*)((char*)d_ws + q32);                      // +24 MB

    k_seg2  <<<512,  256, 0, stream>>>(x, W_in, b_in, Q);
    k_scan2 <<<512,  256, 0, stream>>>(Q);
    k_apply2<<<512,  256, 0, stream>>>(x, W_in, b_in, W_out, Q, WS2);
    k_reduce<<<1536, 256, 0, stream>>>(x, b_out, WS2, out);
}

// Round 9
// 166.087 us; speedup vs baseline: 1.3047x; 1.2019x over previous
//
#include <hip/hip_runtime.h>

// VersorRotorRNN: B=16, S=256, N=16, D=6, H=16, 32 blades (Cl(5,0)).
// Segmented parallel scan over S (SEGT=32, L=8). normalize() is
// scale-invariant; GP bilinear+associative -> defer normalization.
//
// R2+R4: NEVER min-waves>=2 in __launch_bounds__ (VGPR cap -> spill).
// R5: per-thread LDS weight reads saturate the CU LDS pipe -> no LDS.
// R6: wave-per-h scalar-weight path: VGPR 72-84, conflicts 0, 176.6 total.
// R7/R8: outer-loop unroll + gp_step restructure regressed apply 55->71 us
//   (code bloat ~80KB vs 32KB I$; absolute VALU-busy grew). Keep R6 bodies.
// R9: FUSE seg+scan+apply into one kernel. Scan is 32-wide -> in-wave KS
//   (wave = 2 chains x 32 segments). Q workspace + 2 launches eliminated;
//   prefix never leaves registers. R6 inner code verbatim.

#define EPS 1e-8f

struct SgnTab { float v[32][32]; };
constexpr SgnTab make_sgn() {
    SgnTab t{};
    for (int i = 0; i < 32; ++i)
        for (int j = 0; j < 32; ++j) {
            int a = i >> 1, s = 0;
            while (a) {
                int x = a & j;
                while (x) { s += x & 1; x >>= 1; }
                a >>= 1;
            }
            t.v[i][j] = (s & 1) ? -1.0f : 1.0f;
        }
    return t;
}
__device__ constexpr SgnTab SG = make_sgn();

__device__ __forceinline__ float inv_norm(const float* v) {
    float s0 = 0.f, s1 = 0.f, s2 = 0.f, s3 = 0.f;
#pragma unroll
    for (int k = 0; k < 32; k += 4) {
        s0 = fmaf(v[k],     v[k],     s0);
        s1 = fmaf(v[k + 1], v[k + 1], s1);
        s2 = fmaf(v[k + 2], v[k + 2], s2);
        s3 = fmaf(v[k + 3], v[k + 3], s3);
    }
    return rsqrtf((s0 + s1) + (s2 + s3) + EPS);
}

// u8 = chunk c8 of  b_in[h] + x.W_in[:, h*32+..]  (+1 on blade 0)
__device__ __forceinline__ void build_u8_s(const float* __restrict__ Wh,
                                           const float* __restrict__ Bh,
                                           int c8, const float xv[6], float u8[8]) {
#pragma unroll
    for (int l = 0; l < 8; ++l) u8[l] = Bh[c8 * 8 + l];
#pragma unroll
    for (int d = 0; d < 6; ++d)
#pragma unroll
        for (int l = 0; l < 8; ++l)
            u8[l] = fmaf(xv[d], Wh[d * 512 + c8 * 8 + l], u8[l]);
    if (c8 == 0) u8[0] += 1.0f;
}

// np += (u8 chunk c8) (x) R : np[i^j] += sgn(i,j)*u8[l]*R[j], i=c8*8+l
__device__ __forceinline__ void gp_chunk(float* __restrict__ np,
                                         const float u8[8],
                                         const float* __restrict__ R, int c8) {
#pragma unroll
    for (int l = 0; l < 8; ++l) {
        const int i = c8 * 8 + l;
#pragma unroll
        for (int j = 0; j < 32; ++j)
            np[i ^ j] = fmaf(SG.v[i][j] * u8[l], R[j], np[i ^ j]);
    }
}

// Wave wid: h = wid&15 (wave-uniform weights -> scalar loads, no LDS),
//   pair p = wid>>4 (0..127). Lane: sc = lane&31 (segment), chain bit
//   lane>>5 -> bn = p*2 + (lane>>5); b = bn>>4, n = bn&15.
// Phase 1: 8-step segment product (registers). Phase 2: in-wave KS scan
//   over sc (width 32). Phase 3: apply + project, partials to WS2.
__global__ __launch_bounds__(256, 1) void k_fused(
        const float* __restrict__ x, const float* __restrict__ W_in,
        const float* __restrict__ b_in, const float* __restrict__ W_out,
        float* __restrict__ WS2) {
    const int lane = threadIdx.x & 63;
    const int wid = __builtin_amdgcn_readfirstlane(
        (int)(blockIdx.x * 4 + (threadIdx.x >> 6)));
    const int h = wid & 15, p = wid >> 4;
    const int sc = lane & 31;
    const int bn = p * 2 + (lane >> 5), b = bn >> 4, n = bn & 15;
    const float* __restrict__ Wh = W_in + h * 32;  // [d*512 + c]
    const float* __restrict__ Bh = b_in + h * 32;
    const float* __restrict__ Oh = W_out + h * 192;  // [k*6 + d]

    // ---------- phase 1: segment product over t = sc*8 .. sc*8+7 ----------
    float P[32];
    {   // step 0: P = u_0  (1 (x) u = u)
        const int t = sc * 8;
        const float2* xp = (const float2*)(x + ((b * 256 + t) * 16 + n) * 6);
        float2 x01 = xp[0], x23 = xp[1], x45 = xp[2];
        const float xv[6] = {x01.x, x01.y, x23.x, x23.y, x45.x, x45.y};
#pragma unroll
        for (int c8 = 0; c8 < 4; ++c8) build_u8_s(Wh, Bh, c8, xv, P + c8 * 8);
    }
    for (int i = 1; i < 8; ++i) {
        const int t = sc * 8 + i;
        const float2* xp = (const float2*)(x + ((b * 256 + t) * 16 + n) * 6);
        float2 x01 = xp[0], x23 = xp[1], x45 = xp[2];
        const float xv[6] = {x01.x, x01.y, x23.x, x23.y, x45.x, x45.y};
        float np[32];
#pragma unroll
        for (int k = 0; k < 32; ++k) np[k] = 0.0f;
#pragma unroll
        for (int c8 = 0; c8 < 4; ++c8) {
            float u8[8];
            build_u8_s(Wh, Bh, c8, xv, u8);
            gp_chunk(np, u8, P, c8);
        }
#pragma unroll
        for (int k = 0; k < 32; ++k) P[k] = np[k];  // raw; norm deferred
    }
    {   // normalize once before the scan
        float rs = inv_norm(P);
#pragma unroll
        for (int k = 0; k < 32; ++k) P[k] *= rs;
    }

    // ---------- phase 2: Kogge-Stone inclusive scan over sc (width 32) ----
#pragma unroll
    for (int k = 1; k < 32; k <<= 1) {
        float pr[32];
#pragma unroll
        for (int j = 0; j < 32; ++j) pr[j] = __shfl_up(P[j], k, 32);
        if (sc >= k) {
            float np[32];
#pragma unroll
            for (int m = 0; m < 32; ++m) np[m] = 0.0f;
#pragma unroll
            for (int i = 0; i < 32; ++i)
#pragma unroll
                for (int j = 0; j < 32; ++j)
                    np[i ^ j] = fmaf(SG.v[i][j] * P[i], pr[j], np[i ^ j]);
#pragma unroll
            for (int m = 0; m < 32; ++m) P[m] = np[m];
        }
    }
    {   // single normalization of the inclusive prefix
        float rs = inv_norm(P);
#pragma unroll
        for (int j = 0; j < 32; ++j) P[j] *= rs;
    }
    // exclusive shift by one
    float R[32];
#pragma unroll
    for (int j = 0; j < 32; ++j) R[j] = __shfl_up(P[j], 1, 32);
    if (sc == 0) {
#pragma unroll
        for (int j = 0; j < 32; ++j) R[j] = 0.0f;
        R[0] = 1.0f;  // identity rotor
    }

    // ---------- phase 3: apply interior + project ----------
    for (int i = 0; i < 8; ++i) {
        const int t = sc * 8 + i;
        const float2* xp = (const float2*)(x + ((b * 256 + t) * 16 + n) * 6);
        float2 x01 = xp[0], x23 = xp[1], x45 = xp[2];
        const float xv[6] = {x01.x, x01.y, x23.x, x23.y, x45.x, x45.y};
        float np[32];
#pragma unroll
        for (int k = 0; k < 32; ++k) np[k] = 0.0f;
#pragma unroll
        for (int c8 = 0; c8 < 4; ++c8) {
            float u8[8];
            build_u8_s(Wh, Bh, c8, xv, u8);
            gp_chunk(np, u8, R, c8);
        }
        float rs = inv_norm(np);     // fold psi normalization into pd
        float pd[6] = {0.f, 0.f, 0.f, 0.f, 0.f, 0.f};
#pragma unroll
        for (int k = 0; k < 32; ++k)
#pragma unroll
            for (int d = 0; d < 6; ++d)
                pd[d] = fmaf(np[k], Oh[k * 6 + d], pd[d]);
#pragma unroll
        for (int k = 0; k < 32; ++k) R[k] = np[k];  // carry raw psi
        float2* wp = (float2*)(WS2 + (((t * 16 + h) * 256) + bn) * 6);
        wp[0] = make_float2(pd[0] * rs, pd[1] * rs);
        wp[1] = make_float2(pd[2] * rs, pd[3] * rs);
        wp[2] = make_float2(pd[4] * rs, pd[5] * rs);
    }
}

// out[o] = x[o] + b_out[d] + sum_h WS2[t][h][bn][d]   (o = ((b*256+t)*16+n)*6+d)
__global__ __launch_bounds__(256, 1) void k_reduce(
        const float* __restrict__ x, const float* __restrict__ b_out,
        const float* __restrict__ WS2, float* __restrict__ out) {
    const int o = blockIdx.x * 256 + threadIdx.x;  // 393216 total
    const int d = o % 6;
    const int r = o / 6;
    const int n = r & 15;
    const int r2 = r >> 4;
    const int t = r2 & 255;
    const int b = r2 >> 8;
    const int bn = b * 16 + n;
    float acc = x[o] + b_out[d];
#pragma unroll
    for (int h = 0; h < 16; ++h)
        acc += WS2[(((t * 16 + h) * 256) + bn) * 6 + d];
    out[o] = acc;
}

extern "C" void kernel_launch(void* const* d_in, const int* in_sizes, int n_in,
                              void* d_out, int out_size, void* d_ws, size_t ws_size,
                              hipStream_t stream) {
    (void)in_sizes; (void)n_in; (void)out_size; (void)ws_size;
    const float* x     = (const float*)d_in[0];  // [16,256,16,6]
    const float* W_in  = (const float*)d_in[1];  // [6,512]
    const float* b_in  = (const float*)d_in[2];  // [512]
    const float* W_out = (const float*)d_in[3];  // [512,6]
    const float* b_out = (const float*)d_in[4];  // [6]
    float* out = (float*)d_out;                  // [16,256,16,6]
    float* WS2 = (float*)d_ws;                   // 24 MB partials

    k_fused <<<512,  256, 0, stream>>>(x, W_in, b_in, W_out, WS2);
    k_reduce<<<1536, 256, 0, stream>>>(x, b_out, WS2, out);
}

// Round 10
// 144.729 us; speedup vs baseline: 1.4973x; 1.1476x over previous
//
#include <hip/hip_runtime.h>

// VersorRotorRNN: B=16, S=256, N=16, D=6, H=16, 32 blades (Cl(5,0)).
// Segmented parallel scan over S (SEGT=32, L=8) + CENTER SPLIT:
// Cl(5,0) = P+Cl (+) P-Cl via central idempotents P± = (1±w)/2, w=e12345
// (w central, w^2=+1). Each eigenspace is 16-dim; even-blade masks in
// compact 4-bit coords XOR, so GP = two 16x16 signed XOR-convs = 512 FMA
// (vs 1024). Butterfly A±_c = a_m ± sgn(m^31,31) a_{m^31} is exact and
// absorbed into pre-transformed weights (k_prep). |a|^2 = (S+ + S-)/2.
//
// R2+R4: NEVER min-waves>=2 in __launch_bounds__ (VGPR cap -> spill).
// R5: no per-thread LDS weight reads (LDS pipe saturates) -> scalar loads.
// R7/R8: don't unroll outer step loops (I$ bloat) -> rolled, R6 style.
// R9: fused seg+scan+apply, VALUBusy 74% @ VGPR 96 -> now cut VALU work.

#define EPS 1e-8f

constexpr int pcnt(int v) { int s = 0; while (v) { s += v & 1; v >>= 1; } return s; }
constexpr float sgnf(int a, int b) {
    a >>= 1; int s = 0;
    while (a) { s += pcnt(a & b); a >>= 1; }
    return (s & 1) ? -1.0f : 1.0f;
}
struct Tab16 {
    float sg2[16][16];  // sgn(m(c1), m(c2)) : compact-index Cayley signs
    float sig[16];      // sgn(m(c)^31, 31)  : odd-partner collapse sign
    int   cm[16];       // compact -> even blade mask (bit4 = parity(low4))
};
constexpr Tab16 make16() {
    Tab16 t{};
    for (int c = 0; c < 16; ++c) {
        int m = c | ((pcnt(c) & 1) << 4);
        t.cm[c] = m;
        t.sig[c] = sgnf(m ^ 31, 31);
    }
    for (int i = 0; i < 16; ++i)
        for (int j = 0; j < 16; ++j)
            t.sg2[i][j] = sgnf(t.cm[i], t.cm[j]);
    return t;
}
__device__ constexpr Tab16 T16 = make16();

// ---- prep: eigen-transform W_in/b_in per (h, sign) ----
// WP layout per h (224 floats): [sign(2)][ d(6)*16 + c | 96 + c(bias) ]
__global__ __launch_bounds__(256, 1) void k_prep(
        const float* __restrict__ W_in, const float* __restrict__ b_in,
        float* __restrict__ WP) {
    const int idx = blockIdx.x * 256 + threadIdx.x;
    if (idx >= 16 * 224) return;
    const int h = idx / 224, r = idx % 224;
    const int sg = r / 112, r2 = r % 112;
    const float pm = sg ? -1.0f : 1.0f;
    float val;
    if (r2 < 96) {
        const int d = r2 >> 4, c = r2 & 15, m = T16.cm[c];
        val = W_in[d * 512 + h * 32 + m]
            + pm * T16.sig[c] * W_in[d * 512 + h * 32 + (m ^ 31)];
    } else {
        const int c = r2 - 96, m = T16.cm[c];
        val = b_in[h * 32 + m] + pm * T16.sig[c] * b_in[h * 32 + (m ^ 31)];
    }
    WP[idx] = val;
}

// U[c] = bias±[c] + sum_d xv[d]*W±[d][c]  (+1 on c=0: scalar -> both signs)
__device__ __forceinline__ void build_u16(const float* __restrict__ Wsp,
                                          const float xv[6], float U[16]) {
#pragma unroll
    for (int c = 0; c < 16; ++c) U[c] = Wsp[96 + c];
#pragma unroll
    for (int d = 0; d < 6; ++d)
#pragma unroll
        for (int c = 0; c < 16; ++c)
            U[c] = fmaf(xv[d], Wsp[d * 16 + c], U[c]);
    U[0] += 1.0f;  // delta_r's +1 (scalar blade lands in both eigenspaces)
}

// np += U (x) R in one eigenspace: np[c1^c2] += sg2[c1][c2]*U[c1]*R[c2]
__device__ __forceinline__ void gp16(float* __restrict__ np,
                                     const float* __restrict__ U,
                                     const float* __restrict__ R) {
#pragma unroll
    for (int c1 = 0; c1 < 16; ++c1)
#pragma unroll
        for (int c2 = 0; c2 < 16; ++c2)
            np[c1 ^ c2] = fmaf(T16.sg2[c1][c2] * U[c1], R[c2], np[c1 ^ c2]);
}

__device__ __forceinline__ float ssum32(const float* a, const float* b) {
    float s0 = 0.f, s1 = 0.f, s2 = 0.f, s3 = 0.f;
#pragma unroll
    for (int k = 0; k < 16; k += 4) {
        s0 = fmaf(a[k],     a[k],     s0); s1 = fmaf(a[k + 1], a[k + 1], s1);
        s2 = fmaf(a[k + 2], a[k + 2], s2); s3 = fmaf(a[k + 3], a[k + 3], s3);
        s0 = fmaf(b[k],     b[k],     s0); s1 = fmaf(b[k + 1], b[k + 1], s1);
        s2 = fmaf(b[k + 2], b[k + 2], s2); s3 = fmaf(b[k + 3], b[k + 3], s3);
    }
    return (s0 + s1) + (s2 + s3);   // |a|^2_blades = 0.5 * ssum32
}

// Wave wid: h = wid&15 (wave-uniform weights -> scalar loads, no LDS),
//   pair p = wid>>4. Lane: sc = lane&31 (segment), bn = p*2 + (lane>>5).
__global__ __launch_bounds__(256, 1) void k_fused(
        const float* __restrict__ x, const float* __restrict__ WP,
        const float* __restrict__ W_out, float* __restrict__ WS2) {
    const int lane = threadIdx.x & 63;
    const int wid = __builtin_amdgcn_readfirstlane(
        (int)(blockIdx.x * 4 + (threadIdx.x >> 6)));
    const int h = wid & 15, p = wid >> 4;
    const int sc = lane & 31;
    const int bn = p * 2 + (lane >> 5), b = bn >> 4, n = bn & 15;
    const float* __restrict__ Wp0 = WP + h * 224;        // sign +
    const float* __restrict__ Wp1 = WP + h * 224 + 112;  // sign -
    const float* __restrict__ Oh  = W_out + h * 192;     // [k*6 + d]

    // ---------- phase 1: segment product over t = sc*8 .. sc*8+7 ----------
    float Ap[16], Am[16];
    {   // step 0: psi = u_0
        const int t = sc * 8;
        const float2* xp = (const float2*)(x + ((b * 256 + t) * 16 + n) * 6);
        float2 x01 = xp[0], x23 = xp[1], x45 = xp[2];
        const float xv[6] = {x01.x, x01.y, x23.x, x23.y, x45.x, x45.y};
        build_u16(Wp0, xv, Ap);
        build_u16(Wp1, xv, Am);
    }
    for (int i = 1; i < 8; ++i) {
        const int t = sc * 8 + i;
        const float2* xp = (const float2*)(x + ((b * 256 + t) * 16 + n) * 6);
        float2 x01 = xp[0], x23 = xp[1], x45 = xp[2];
        const float xv[6] = {x01.x, x01.y, x23.x, x23.y, x45.x, x45.y};
        float U[16], np[16];
        build_u16(Wp0, xv, U);
#pragma unroll
        for (int k = 0; k < 16; ++k) np[k] = 0.0f;
        gp16(np, U, Ap);
#pragma unroll
        for (int k = 0; k < 16; ++k) Ap[k] = np[k];
        build_u16(Wp1, xv, U);
#pragma unroll
        for (int k = 0; k < 16; ++k) np[k] = 0.0f;
        gp16(np, U, Am);
#pragma unroll
        for (int k = 0; k < 16; ++k) Am[k] = np[k];
    }
    {   // normalize once before the scan
        float rs = rsqrtf(0.5f * ssum32(Ap, Am) + EPS);
#pragma unroll
        for (int k = 0; k < 16; ++k) { Ap[k] *= rs; Am[k] *= rs; }
    }

    // ---------- phase 2: Kogge-Stone inclusive scan over sc (width 32) ----
#pragma unroll
    for (int k = 1; k < 32; k <<= 1) {
        float prp[16], prm[16];
#pragma unroll
        for (int j = 0; j < 16; ++j) {
            prp[j] = __shfl_up(Ap[j], k, 32);
            prm[j] = __shfl_up(Am[j], k, 32);
        }
        if (sc >= k) {
            float np[16];
#pragma unroll
            for (int m = 0; m < 16; ++m) np[m] = 0.0f;
            gp16(np, Ap, prp);      // later range on the left
#pragma unroll
            for (int m = 0; m < 16; ++m) Ap[m] = np[m];
#pragma unroll
            for (int m = 0; m < 16; ++m) np[m] = 0.0f;
            gp16(np, Am, prm);
#pragma unroll
            for (int m = 0; m < 16; ++m) Am[m] = np[m];
        }
    }
    {   // single normalization of the inclusive prefix
        float rs = rsqrtf(0.5f * ssum32(Ap, Am) + EPS);
#pragma unroll
        for (int j = 0; j < 16; ++j) { Ap[j] *= rs; Am[j] *= rs; }
    }
    // exclusive shift by one
    float Rp[16], Rm[16];
#pragma unroll
    for (int j = 0; j < 16; ++j) {
        Rp[j] = __shfl_up(Ap[j], 1, 32);
        Rm[j] = __shfl_up(Am[j], 1, 32);
    }
    if (sc == 0) {
#pragma unroll
        for (int j = 0; j < 16; ++j) { Rp[j] = 0.0f; Rm[j] = 0.0f; }
        Rp[0] = 1.0f; Rm[0] = 1.0f;  // identity rotor = P+ + P-
    }

    // ---------- phase 3: apply interior + project ----------
    for (int i = 0; i < 8; ++i) {
        const int t = sc * 8 + i;
        const float2* xp = (const float2*)(x + ((b * 256 + t) * 16 + n) * 6);
        float2 x01 = xp[0], x23 = xp[1], x45 = xp[2];
        const float xv[6] = {x01.x, x01.y, x23.x, x23.y, x45.x, x45.y};
        float U[16], npp[16], npm[16];
        build_u16(Wp0, xv, U);
#pragma unroll
        for (int k = 0; k < 16; ++k) npp[k] = 0.0f;
        gp16(npp, U, Rp);
        build_u16(Wp1, xv, U);
#pragma unroll
        for (int k = 0; k < 16; ++k) npm[k] = 0.0f;
        gp16(npm, U, Rm);
        // pd from blade reconstruction; 0.5 recon factor folded into rs
        float rs = 0.5f * rsqrtf(0.5f * ssum32(npp, npm) + EPS);
        float pd[6] = {0.f, 0.f, 0.f, 0.f, 0.f, 0.f};
#pragma unroll
        for (int c = 0; c < 16; ++c) {
            const int m = T16.cm[c];
            const float ev = npp[c] + npm[c];              // 2*a_even
            const float od = T16.sig[c] * (npp[c] - npm[c]); // 2*a_odd
#pragma unroll
            for (int d = 0; d < 6; ++d) {
                pd[d] = fmaf(ev, Oh[m * 6 + d], pd[d]);
                pd[d] = fmaf(od, Oh[(m ^ 31) * 6 + d], pd[d]);
            }
        }
#pragma unroll
        for (int k = 0; k < 16; ++k) { Rp[k] = npp[k]; Rm[k] = npm[k]; }
        float2* wp = (float2*)(WS2 + (((t * 16 + h) * 256) + bn) * 6);
        wp[0] = make_float2(pd[0] * rs, pd[1] * rs);
        wp[1] = make_float2(pd[2] * rs, pd[3] * rs);
        wp[2] = make_float2(pd[4] * rs, pd[5] * rs);
    }
}

// out[o] = x[o] + b_out[d] + sum_h WS2[t][h][bn][d]   (o = ((b*256+t)*16+n)*6+d)
__global__ __launch_bounds__(256, 1) void k_reduce(
        const float* __restrict__ x, const float* __restrict__ b_out,
        const float* __restrict__ WS2, float* __restrict__ out) {
    const int o = blockIdx.x * 256 + threadIdx.x;  // 393216 total
    const int d = o % 6;
    const int r = o / 6;
    const int n = r & 15;
    const int r2 = r >> 4;
    const int t = r2 & 255;
    const int b = r2 >> 8;
    const int bn = b * 16 + n;
    float acc = x[o] + b_out[d];
#pragma unroll
    for (int h = 0; h < 16; ++h)
        acc += WS2[(((t * 16 + h) * 256) + bn) * 6 + d];
    out[o] = acc;
}

extern "C" void kernel_launch(void* const* d_in, const int* in_sizes, int n_in,
                              void* d_out, int out_size, void* d_ws, size_t ws_size,
                              hipStream_t stream) {
    (void)in_sizes; (void)n_in; (void)out_size; (void)ws_size;
    const float* x     = (const float*)d_in[0];  // [16,256,16,6]
    const float* W_in  = (const float*)d_in[1];  // [6,512]
    const float* b_in  = (const float*)d_in[2];  // [512]
    const float* W_out = (const float*)d_in[3];  // [512,6]
    const float* b_out = (const float*)d_in[4];  // [6]
    float* out = (float*)d_out;                  // [16,256,16,6]

    float* WP  = (float*)d_ws;                         // 16*224 floats (14 KB)
    float* WS2 = (float*)((char*)d_ws + 16384);        // 24 MB partials

    k_prep  <<<14,   256, 0, stream>>>(W_in, b_in, WP);
    k_fused <<<512,  256, 0, stream>>>(x, WP, W_out, WS2);
    k_reduce<<<1536, 256, 0, stream>>>(x, b_out, WS2, out);
}